// Round 1
// baseline (77.881 us; speedup 1.0000x reference)
//
#include <hip/hip_runtime.h>

typedef float f32x4 __attribute__((ext_vector_type(4)));

#define MDIM 8192
#define NDIM 8192
#define KDIM 64

// ---------------- quantize q: fp32 [M][64] -> fp8 [M][64] ----------------
__global__ __launch_bounds__(256) void quant_q(const float* __restrict__ in,
                                               int* __restrict__ out) {
    int i = blockIdx.x * 256 + threadIdx.x;          // one float4 -> 4 fp8 bytes
    const float4* p = reinterpret_cast<const float4*>(in);
    float4 v = p[i];
    int r = __builtin_amdgcn_cvt_pk_fp8_f32(v.x, v.y, 0, false);
    r     = __builtin_amdgcn_cvt_pk_fp8_f32(v.z, v.w, r, true);
    out[i] = r;
}

// ------- quantize + transpose k: fp32 [64][N] -> fp8 kT [N][64] ----------
__global__ __launch_bounds__(256) void quant_k_t(const float* __restrict__ k,
                                                 int4* __restrict__ kt) {
    int n = blockIdx.x * 256 + threadIdx.x;          // 8192 threads, one per column
    int pk[16];
#pragma unroll
    for (int j = 0; j < 16; ++j) {
        // coalesced across lanes (consecutive n), 4 k-rows per iter
        float v0 = k[(size_t)(4 * j + 0) * NDIM + n];
        float v1 = k[(size_t)(4 * j + 1) * NDIM + n];
        float v2 = k[(size_t)(4 * j + 2) * NDIM + n];
        float v3 = k[(size_t)(4 * j + 3) * NDIM + n];
        int r = __builtin_amdgcn_cvt_pk_fp8_f32(v0, v1, 0, false);
        pk[j] = __builtin_amdgcn_cvt_pk_fp8_f32(v2, v3, r, true);
    }
#pragma unroll
    for (int s = 0; s < 4; ++s) {
        int4 w = make_int4(pk[4 * s + 0], pk[4 * s + 1], pk[4 * s + 2], pk[4 * s + 3]);
        kt[(size_t)n * 4 + s] = w;                   // 64B row per column n
    }
}

// ---------------- GEMM: C[M][N] = A8[M][64] * (kT8[N][64])^T -------------
// block = 256 threads (4 waves), block tile 64x64, wave tile 16x64.
// All-register, no LDS. 8 MFMAs per wave (4 N-tiles x 2 K-steps of 32).
__global__ __launch_bounds__(256) void gemm_fp8(const unsigned char* __restrict__ A8,
                                                const unsigned char* __restrict__ BT8,
                                                float* __restrict__ C) {
    const int bx   = blockIdx.x;          // N tile (fastest -> store locality)
    const int by   = blockIdx.y;          // M tile
    const int wave = threadIdx.x >> 6;
    const int lane = threadIdx.x & 63;
    const int r    = lane & 15;           // row (A) / col (B) within 16
    const int ko   = (lane >> 4) * 8;     // k byte offset: 0,8,16,24

    // A fragment: row = by*64 + wave*16 + r, bytes [ko, ko+8) and [ko+32, ko+40)
    const size_t arow = (size_t)(by * 64 + wave * 16 + r) * KDIM;
    const long a0 = *reinterpret_cast<const long*>(A8 + arow + ko);
    const long a1 = *reinterpret_cast<const long*>(A8 + arow + ko + 32);

    f32x4 acc[4] = {};
#pragma unroll
    for (int n = 0; n < 4; ++n) {
        const size_t brow = (size_t)(bx * 64 + n * 16 + r) * KDIM;
        const long b0 = *reinterpret_cast<const long*>(BT8 + brow + ko);
        const long b1 = *reinterpret_cast<const long*>(BT8 + brow + ko + 32);
        acc[n] = __builtin_amdgcn_mfma_f32_16x16x32_fp8_fp8(a0, b0, acc[n], 0, 0, 0);
        acc[n] = __builtin_amdgcn_mfma_f32_16x16x32_fp8_fp8(a1, b1, acc[n], 0, 0, 0);
    }

    // C/D layout (16x16, dtype-independent): col = lane&15, row = (lane>>4)*4 + i
    const int row0 = by * 64 + wave * 16 + (lane >> 4) * 4;
    const int col0 = bx * 64 + (lane & 15);
#pragma unroll
    for (int n = 0; n < 4; ++n) {
#pragma unroll
        for (int i = 0; i < 4; ++i) {
            C[(size_t)(row0 + i) * NDIM + col0 + n * 16] = acc[n][i];
        }
    }
}

extern "C" void kernel_launch(void* const* d_in, const int* in_sizes, int n_in,
                              void* d_out, int out_size, void* d_ws, size_t ws_size,
                              hipStream_t stream) {
    const float* q = (const float*)d_in[0];   // [8192][64] fp32
    const float* k = (const float*)d_in[1];   // [64][8192] fp32
    float* C = (float*)d_out;                 // [8192][8192] fp32

    unsigned char* q8  = (unsigned char*)d_ws;                   // 512 KB
    unsigned char* kt8 = q8 + (size_t)MDIM * KDIM;               // 512 KB

    // q: 8192*64 = 524288 floats = 131072 float4s -> 512 blocks
    hipLaunchKernelGGL(quant_q, dim3(512), dim3(256), 0, stream, q, (int*)q8);
    // k: 8192 columns -> 32 blocks
    hipLaunchKernelGGL(quant_k_t, dim3(32), dim3(256), 0, stream, k, (int4*)kt8);
    // gemm: 128x128 blocks of 64x64 output
    hipLaunchKernelGGL(gemm_fp8, dim3(NDIM / 64, MDIM / 64), dim3(256), 0, stream,
                       q8, kt8, C);
}

// Round 2
// 53.154 us; speedup vs baseline: 1.4652x; 1.4652x over previous
//
#include <hip/hip_runtime.h>

typedef float f32x4 __attribute__((ext_vector_type(4)));

#define MDIM 8192
#define NDIM 8192
#define KDIM 64

#define BM 32
#define BN 256
#define LSTR 260   // LDS row stride in dwords (32 rows x 260 x 4B = 33 KB)

// ---------------- quantize q: fp32 [M][64] -> fp8 [M][64] ----------------
__global__ __launch_bounds__(256) void quant_q(const float* __restrict__ in,
                                               int* __restrict__ out) {
    int i = blockIdx.x * 256 + threadIdx.x;          // one float4 -> 4 fp8 bytes
    const float4* p = reinterpret_cast<const float4*>(in);
    float4 v = p[i];
    int r = __builtin_amdgcn_cvt_pk_fp8_f32(v.x, v.y, 0, false);
    r     = __builtin_amdgcn_cvt_pk_fp8_f32(v.z, v.w, r, true);
    out[i] = r;
}

// ------- quantize + transpose k: fp32 [64][N] -> fp8 kT [N][64] ----------
// grid (32, 4): x = column block, y = k-quarter. Thread handles 16 k-rows
// of one column -> one int4 store. 128 blocks (was 32).
__global__ __launch_bounds__(256) void quant_k_t(const float* __restrict__ k,
                                                 int4* __restrict__ kt) {
    int n = blockIdx.x * 256 + threadIdx.x;          // column 0..8191
    int q = blockIdx.y;                              // k quarter 0..3
    int pk[4];
#pragma unroll
    for (int j = 0; j < 4; ++j) {
        int row = q * 16 + j * 4;
        float v0 = k[(size_t)(row + 0) * NDIM + n];  // coalesced across lanes
        float v1 = k[(size_t)(row + 1) * NDIM + n];
        float v2 = k[(size_t)(row + 2) * NDIM + n];
        float v3 = k[(size_t)(row + 3) * NDIM + n];
        int r = __builtin_amdgcn_cvt_pk_fp8_f32(v0, v1, 0, false);
        pk[j] = __builtin_amdgcn_cvt_pk_fp8_f32(v2, v3, r, true);
    }
    kt[(size_t)n * 4 + q] = make_int4(pk[0], pk[1], pk[2], pk[3]);
}

// ---------------- GEMM: C[M][N] = A8[M][64] * (kT8[N][64])^T -------------
// block = 256 threads (4 waves), block tile 32(M) x 256(N), wave tile 32x64.
// 16 MFMAs per wave. Epilogue stages the 32x256 fp32 tile in LDS, then
// streams it out as full 1KB-contiguous rows (1 row per wave per dwordx4).
__global__ __launch_bounds__(256) void gemm_fp8(const unsigned char* __restrict__ A8,
                                                const unsigned char* __restrict__ BT8,
                                                float* __restrict__ C) {
    __shared__ float lds[BM * LSTR];

    const int w    = threadIdx.x >> 6;    // wave 0..3 (owns N-slice w*64)
    const int lane = threadIdx.x & 63;
    const int r    = lane & 15;           // row (A) / col (B) within 16
    const int g    = lane >> 4;           // lane group 0..3
    const int ko   = g * 8;               // k byte offset: 0,8,16,24

    const int bx = blockIdx.x;            // N tile (32)
    const int by = blockIdx.y;            // M tile (256)
    const int rowbase = by * BM;
    const int colbase = bx * BN;

    // A fragments: m-tile 0..1, k-step 0..1
    long a[2][2];
#pragma unroll
    for (int m = 0; m < 2; ++m) {
        const size_t arow = (size_t)(rowbase + m * 16 + r) * KDIM;
        a[m][0] = *reinterpret_cast<const long*>(A8 + arow + ko);
        a[m][1] = *reinterpret_cast<const long*>(A8 + arow + ko + 32);
    }
    // B fragments: n-tile 0..3 within this wave's 64-col slice
    long b[4][2];
#pragma unroll
    for (int n = 0; n < 4; ++n) {
        const size_t brow = (size_t)(colbase + w * 64 + n * 16 + r) * KDIM;
        b[n][0] = *reinterpret_cast<const long*>(BT8 + brow + ko);
        b[n][1] = *reinterpret_cast<const long*>(BT8 + brow + ko + 32);
    }

    f32x4 acc[2][4] = {};
#pragma unroll
    for (int m = 0; m < 2; ++m)
#pragma unroll
        for (int n = 0; n < 4; ++n) {
            acc[m][n] = __builtin_amdgcn_mfma_f32_16x16x32_fp8_fp8(a[m][0], b[n][0], acc[m][n], 0, 0, 0);
            acc[m][n] = __builtin_amdgcn_mfma_f32_16x16x32_fp8_fp8(a[m][1], b[n][1], acc[m][n], 0, 0, 0);
        }

    // Stage tile in LDS. C/D layout: col = lane&15, row = g*4 + i.
#pragma unroll
    for (int m = 0; m < 2; ++m)
#pragma unroll
        for (int n = 0; n < 4; ++n) {
            const int row = m * 16 + g * 4;
            const int col = w * 64 + n * 16 + r;
#pragma unroll
            for (int i = 0; i < 4; ++i)
                lds[(row + i) * LSTR + col] = acc[m][n][i];
        }

    __syncthreads();

    // Stream out: round p writes rows p*4 .. p*4+3; each wave = 1 full row
    // = 64 lanes x 16B = 1KB contiguous.
#pragma unroll
    for (int p = 0; p < 8; ++p) {
        const int row  = p * 4 + w;
        const int col4 = lane * 4;
        float4 v = *reinterpret_cast<const float4*>(&lds[row * LSTR + col4]);
        *reinterpret_cast<float4*>(&C[(size_t)(rowbase + row) * NDIM + colbase + col4]) = v;
    }
}

extern "C" void kernel_launch(void* const* d_in, const int* in_sizes, int n_in,
                              void* d_out, int out_size, void* d_ws, size_t ws_size,
                              hipStream_t stream) {
    const float* q = (const float*)d_in[0];   // [8192][64] fp32
    const float* k = (const float*)d_in[1];   // [64][8192] fp32
    float* C = (float*)d_out;                 // [8192][8192] fp32

    unsigned char* q8  = (unsigned char*)d_ws;                   // 512 KB
    unsigned char* kt8 = q8 + (size_t)MDIM * KDIM;               // 512 KB

    hipLaunchKernelGGL(quant_q, dim3(512), dim3(256), 0, stream, q, (int*)q8);
    hipLaunchKernelGGL(quant_k_t, dim3(32, 4), dim3(256), 0, stream, k, (int4*)kt8);
    hipLaunchKernelGGL(gemm_fp8, dim3(NDIM / BN, MDIM / BM), dim3(256), 0, stream,
                       q8, kt8, C);
}

// Round 4
// 50.135 us; speedup vs baseline: 1.5534x; 1.0602x over previous
//
#include <hip/hip_runtime.h>

typedef float f32x4 __attribute__((ext_vector_type(4)));

#define MDIM 8192
#define NDIM 8192
#define KDIM 64

#define BM 32
#define BN 256
#define LSTR 260   // LDS row stride in dwords (32 x 260 x 4B = 33 KB)

// Swizzled fp8 fragment layout, both operands:
//   per 16-row(col) tile: 1024 B = [ks:2][g:4][r:16][8 B], where the 8 B at
//   (ks,g,r) are k-values k = ks*32 + g*8 .. +8 for row(col) r of the tile.
// GEMM fragment load for lane (r,g): one 8 B load at tile*1024 + ks*512 +
//   g*128 + r*8  -> 64 lanes cover 512 B contiguous. Fully coalesced.

__device__ __forceinline__ int pk4(float a, float b, float c, float d) {
    int r = __builtin_amdgcn_cvt_pk_fp8_f32(a, b, 0, false);
    return __builtin_amdgcn_cvt_pk_fp8_f32(c, d, r, true);
}

// ---- fused quantize: blocks [0,128) -> q path, [128,256) -> k path ----
__global__ __launch_bounds__(256) void quant_both(const float* __restrict__ q,
                                                  const float* __restrict__ k,
                                                  int2* __restrict__ q8s,
                                                  int2* __restrict__ k8s) {
    const int bid = blockIdx.x;
    if (bid < 128) {
        // q [8192][64] row-major: thread t handles 16 consecutive floats
        // = row m = t>>2, quarter qq = t&3 (k-range qq*16..+16).
        int t = bid * 256 + threadIdx.x;                 // 32768 threads
        const float4* p = reinterpret_cast<const float4*>(q) + (size_t)t * 4;
        float4 v0 = p[0], v1 = p[1], v2 = p[2], v3 = p[3];
        int p0 = pk4(v0.x, v0.y, v0.z, v0.w);
        int p1 = pk4(v1.x, v1.y, v1.z, v1.w);
        int p2 = pk4(v2.x, v2.y, v2.z, v2.w);
        int p3 = pk4(v3.x, v3.y, v3.z, v3.w);
        int m = t >> 2, qq = t & 3;
        int tile = m >> 4, r = m & 15, ks = qq >> 1, gb = (qq & 1) * 2;
        size_t base = (size_t)tile * 128 + ks * 64 + gb * 16 + r;  // int2 units
        q8s[base]      = make_int2(p0, p1);
        q8s[base + 16] = make_int2(p2, p3);
    } else {
        // k [64][8192] row-major: thread handles col n, quarter qq
        int bb = bid - 128;
        int qq = bb & 3;
        int n  = (bb >> 2) * 256 + threadIdx.x;          // column 0..8191
        int pk[4];
#pragma unroll
        for (int j = 0; j < 4; ++j) {
            int row = qq * 16 + j * 4;
            float v0 = k[(size_t)(row + 0) * NDIM + n];  // coalesced across lanes
            float v1 = k[(size_t)(row + 1) * NDIM + n];
            float v2 = k[(size_t)(row + 2) * NDIM + n];
            float v3 = k[(size_t)(row + 3) * NDIM + n];
            pk[j] = pk4(v0, v1, v2, v3);
        }
        int tile = n >> 4, r = n & 15, ks = qq >> 1, gb = (qq & 1) * 2;
        size_t base = (size_t)tile * 128 + ks * 64 + gb * 16 + r;
        k8s[base]      = make_int2(pk[0], pk[1]);
        k8s[base + 16] = make_int2(pk[2], pk[3]);
    }
}

// ---------------- GEMM: C[M][N] = A * B, swizzled fp8 operands ----------
// block = 256 threads (4 waves), tile 32(M) x 256(N), wave tile 32x64.
// All-register MFMA phase; LDS-staged epilogue streams 1 KB rows.
__global__ __launch_bounds__(256) void gemm_fp8(const long* __restrict__ A8,
                                                const long* __restrict__ B8,
                                                float* __restrict__ C) {
    __shared__ float lds[BM * LSTR];

    const int w    = threadIdx.x >> 6;    // wave 0..3 (N-slice w*64)
    const int lane = threadIdx.x & 63;
    const int r    = lane & 15;
    const int g    = lane >> 4;
    const int fs   = g * 16 + r;          // fragment slot within tile (long units)

    const int bx = blockIdx.x;            // N tile (32)
    const int by = blockIdx.y;            // M tile (256)
    const int rowbase = by * BM;
    const int colbase = bx * BN;

    long a[2][2];
#pragma unroll
    for (int m = 0; m < 2; ++m)
#pragma unroll
        for (int ks = 0; ks < 2; ++ks)
            a[m][ks] = A8[(size_t)((rowbase >> 4) + m) * 128 + ks * 64 + fs];

    long b[4][2];
#pragma unroll
    for (int n = 0; n < 4; ++n)
#pragma unroll
        for (int ks = 0; ks < 2; ++ks)
            b[n][ks] = B8[(size_t)((colbase >> 4) + w * 4 + n) * 128 + ks * 64 + fs];

    f32x4 acc[2][4] = {};
#pragma unroll
    for (int m = 0; m < 2; ++m)
#pragma unroll
        for (int n = 0; n < 4; ++n) {
            acc[m][n] = __builtin_amdgcn_mfma_f32_16x16x32_fp8_fp8(a[m][0], b[n][0], acc[m][n], 0, 0, 0);
            acc[m][n] = __builtin_amdgcn_mfma_f32_16x16x32_fp8_fp8(a[m][1], b[n][1], acc[m][n], 0, 0, 0);
        }

    // Stage in LDS. C/D layout: col = lane&15, row = g*4 + i.
#pragma unroll
    for (int m = 0; m < 2; ++m)
#pragma unroll
        for (int n = 0; n < 4; ++n) {
            const int row = m * 16 + g * 4;
            const int col = w * 64 + n * 16 + r;
#pragma unroll
            for (int i = 0; i < 4; ++i)
                lds[(row + i) * LSTR + col] = acc[m][n][i];
        }

    __syncthreads();

    // Stream out: each wave writes one full 1 KB row per dwordx4 round.
#pragma unroll
    for (int p = 0; p < 8; ++p) {
        const int row  = p * 4 + w;
        const int col4 = lane * 4;
        f32x4 v = *reinterpret_cast<const f32x4*>(&lds[row * LSTR + col4]);
        __builtin_nontemporal_store(
            v, reinterpret_cast<f32x4*>(&C[(size_t)(rowbase + row) * NDIM + colbase + col4]));
    }
}

extern "C" void kernel_launch(void* const* d_in, const int* in_sizes, int n_in,
                              void* d_out, int out_size, void* d_ws, size_t ws_size,
                              hipStream_t stream) {
    const float* q = (const float*)d_in[0];   // [8192][64] fp32
    const float* k = (const float*)d_in[1];   // [64][8192] fp32
    float* C = (float*)d_out;                 // [8192][8192] fp32

    long* q8s = (long*)d_ws;                                  // 512 KB swizzled A
    long* k8s = q8s + (size_t)MDIM * KDIM / 8;                // 512 KB swizzled B

    hipLaunchKernelGGL(quant_both, dim3(256), dim3(256), 0, stream,
                       q, k, (int2*)q8s, (int2*)k8s);
    hipLaunchKernelGGL(gemm_fp8, dim3(NDIM / BN, MDIM / BM), dim3(256), 0, stream,
                       (const long*)q8s, (const long*)k8s, C);
}